// Round 24
// baseline (89.813 us; speedup 1.0000x reference)
//
#include <hip/hip_runtime.h>

#define SEQ 79
#define DM 1024
#define BATCHN 512
#define NPB (SEQ * SEQ)             // 6241
#define P 36                        // k-pitch in floats (16B-aligned, odd/32 banks)
#define NWAVES 4                    // 256-thread block

typedef float v2f   __attribute__((ext_vector_type(2)));
typedef float f32x4 __attribute__((ext_vector_type(4)));
typedef short short8 __attribute__((ext_vector_type(8)));

__device__ __forceinline__ unsigned cvt_pk_bf16(float lo, float hi) {
    unsigned r;
    asm("v_cvt_pk_bf16_f32 %0, %1, %2" : "=v"(r) : "v"(lo), "v"(hi));
    return r;
}

// DPP lane-shuffle add on the VALU pipe: 0xB1=xor1, 0x4E=xor2, 0x124=row_ror:4,
// 0x128=row_ror:8 -> 16-lane sums after 4 steps. (R16-proven.)
template <int CTRL>
__device__ __forceinline__ float dpp_add(float v) {
    int t = __builtin_amdgcn_update_dpp(0, __builtin_bit_cast(int, v),
                                        CTRL, 0xf, 0xf, false);
    return v + __builtin_bit_cast(float, t);
}

__device__ __forceinline__ v2f gelu2(v2f a) {
    // gelu(a) = a - a / (exp2(c1*a + c2*a^3) + 1)
    const v2f C1 = {2.3022585093f, 2.3022585093f};
    const v2f C2 = {0.1029450750f, 0.1029450750f};
    v2f tt = a * (a * a * C2 + C1);
    v2f e;
    e.x = __builtin_amdgcn_exp2f(tt.x);
    e.y = __builtin_amdgcn_exp2f(tt.y);
    v2f ep = e + (v2f){1.f, 1.f};
    v2f r;
    r.x = __builtin_amdgcn_rcpf(ep.x);
    r.y = __builtin_amdgcn_rcpf(ep.y);
    return a - a * r;
}

// R19 body (passing, 68.9us) + TWIN-BLOCK split for 16 waves/CU:
// grid 1024, blocks b and b+512 both serve batch b. 512 = 0 mod 8 ->
// the twin lands on the SAME XCD under round-robin dispatch, so its
// duplicated phase-A x-reads hit that XCD's L2 (R11's failure used
// blocks 2b/2b+1 -> DIFFERENT XCDs -> FETCH doubled to 162MB).
// Each block: full phase A into its own LDS, then HALF of phase B's
// i-range. 4 blocks/CU x 4 waves = 16 waves/CU (= the 88-VGPR HW cap).
// 512-thread blocks are permanently ruled out (R12/R23: SGPR collapse
// to 32 at width 512 regardless of the min-waves arg).
// TRIPWIRE: FETCH ~160MB or dur >= 69us -> revert to R19, assess roofline.
__global__ __launch_bounds__(256) void fused_bias(
    const float* __restrict__ x,
    const float* __restrict__ piece_w, const float* __restrict__ piece_b,
    const float* __restrict__ color_w, const float* __restrict__ color_b,
    const float* __restrict__ mlp1_w,  const float* __restrict__ mlp1_b,
    const float* __restrict__ mlp2_w,  const float* __restrict__ mlp2_b,
    float* __restrict__ out)
{
    __shared__ float uL[80 * P];     // 11,520 B
    __shared__ float vL[80 * P];     // 11,520 B
    __shared__ float colL[80];

    const int tid  = threadIdx.x;
    const int lane = tid & 63;
    const int wv   = tid >> 6;       // wave id 0..3
    const int b    = blockIdx.x & 511;   // batch
    const int half = blockIdx.x >> 9;    // 0 or 1; twin co-XCD with base
    const int k    = lane & 31;
    const bool is_u = (lane < 32);

    // ---- phase-A per-lane projection weights: c = q*256 + lane*4 + t
    float wp[4][4][7];
#pragma unroll
    for (int q = 0; q < 4; ++q)
#pragma unroll
        for (int t = 0; t < 4; ++t) {
            const int c = q * 256 + lane * 4 + t;
#pragma unroll
            for (int e = 0; e < 6; ++e) wp[q][t][e] = piece_w[c * 6 + e];
            wp[q][t][6] = color_w[c];
        }

    float wsp0 = mlp1_w[0 * 32 + k];
    float wsp1 = mlp1_w[1 * 32 + k];
    if (!is_u) { wsp0 = -wsp0; wsp1 = -wsp1; }
    const float bias1 = is_u ? mlp1_b[k] : 0.0f;
    float wc[6];
#pragma unroll
    for (int c = 0; c < 6; ++c)
        wc[c] = mlp1_w[((is_u ? 2 : 8) + c) * 32 + k];
    float pb[6];
#pragma unroll
    for (int e = 0; e < 6; ++e) pb[e] = piece_b[e];
    const float cb = color_b[0];

    // ---- phase-B lane constants
    const int e16 = lane & 15;          // j-in-subtile / W2 output index
    const int kq  = lane >> 4;          // k-quarter
    const int k0  = kq * 8;

    union { unsigned w[4]; short8 s; } A;   // A-frag = W2^T (rows 8..15 zero)
#pragma unroll
    for (int w = 0; w < 4; ++w) {
        const float lo = (e16 < 8) ? mlp2_w[(k0 + 2 * w) * 8 + e16] : 0.0f;
        const float hi = (e16 < 8) ? mlp2_w[(k0 + 2 * w + 1) * 8 + e16] : 0.0f;
        A.w[w] = cvt_pk_bf16(lo, hi);
    }
    v2f w14p[4];
#pragma unroll
    for (int w = 0; w < 4; ++w)
        w14p[w] = (v2f){mlp1_w[14 * 32 + k0 + 2 * w], mlp1_w[14 * 32 + k0 + 2 * w + 1]};
    float b2v[4];
#pragma unroll
    for (int q = 0; q < 4; ++q)
        b2v[q] = (kq < 2) ? mlp2_b[kq * 4 + q] : 0.0f;

    // defined padding for row 79 (j==79 reads feed MFMA col 15, store-guarded)
    if (wv == 0) {
        if (lane < P) vL[79 * P + lane] = 0.0f;
        if (lane == 0) colL[79] = 0.0f;
    }

    // ---------------- Phase A: 79 token rows -> LDS, 2 rows/iteration -------
    const float* xb = x + (size_t)b * SEQ * DM;
    for (int n = wv; n < SEQ; n += 2 * NWAVES) {
        const int n2  = n + NWAVES;
        const int n2c = (n2 < SEQ) ? n2 : n;   // clamped: loads always defined

        // issue all 8 loads up front (row n2's fly under row n's compute)
        const float4* xr0 = (const float4*)(xb + (size_t)n * DM);
        const float4* xr1 = (const float4*)(xb + (size_t)n2c * DM);
        float4 xv0[4], xv1[4];
#pragma unroll
        for (int q = 0; q < 4; ++q) xv0[q] = xr0[q * 64 + lane];
#pragma unroll
        for (int q = 0; q < 4; ++q) xv1[q] = xr1[q * 64 + lane];

        // ---- row n
        {
            float acc[7] = {0.f, 0.f, 0.f, 0.f, 0.f, 0.f, 0.f};
#pragma unroll
            for (int q = 0; q < 4; ++q) {
                const float xs[4] = {xv0[q].x, xv0[q].y, xv0[q].z, xv0[q].w};
#pragma unroll
                for (int t = 0; t < 4; ++t)
#pragma unroll
                    for (int e = 0; e < 7; ++e)
                        acc[e] = fmaf(xs[t], wp[q][t][e], acc[e]);
            }
#pragma unroll
            for (int e = 0; e < 7; ++e) {
                acc[e] = dpp_add<0xB1>(acc[e]);
                acc[e] = dpp_add<0x4E>(acc[e]);
                acc[e] = dpp_add<0x124>(acc[e]);
                acc[e] = dpp_add<0x128>(acc[e]);
                acc[e] += __shfl_xor(acc[e], 16, 64);
                acc[e] += __shfl_xor(acc[e], 32, 64);
            }
            float p[6];
#pragma unroll
            for (int e = 0; e < 6; ++e) p[e] = acc[e] + pb[e];
            const float fx = (n < 64) ? (float)(n >> 3) : 0.0f;
            const float fy = (n < 64) ? (float)(n & 7) : 0.0f;
            float val = bias1;
            val = fmaf(fx, wsp0, val);
            val = fmaf(fy, wsp1, val);
#pragma unroll
            for (int c = 0; c < 6; ++c) val = fmaf(p[c], wc[c], val);
            float* dst = is_u ? uL : vL;
            dst[n * P + k] = val;
            if (lane == 0) colL[n] = acc[6] + cb;
        }

        // ---- row n2 (skipped entirely on the tail; loads were clamped)
        if (n2 < SEQ) {
            float acc[7] = {0.f, 0.f, 0.f, 0.f, 0.f, 0.f, 0.f};
#pragma unroll
            for (int q = 0; q < 4; ++q) {
                const float xs[4] = {xv1[q].x, xv1[q].y, xv1[q].z, xv1[q].w};
#pragma unroll
                for (int t = 0; t < 4; ++t)
#pragma unroll
                    for (int e = 0; e < 7; ++e)
                        acc[e] = fmaf(xs[t], wp[q][t][e], acc[e]);
            }
#pragma unroll
            for (int e = 0; e < 7; ++e) {
                acc[e] = dpp_add<0xB1>(acc[e]);
                acc[e] = dpp_add<0x4E>(acc[e]);
                acc[e] = dpp_add<0x124>(acc[e]);
                acc[e] = dpp_add<0x128>(acc[e]);
                acc[e] += __shfl_xor(acc[e], 16, 64);
                acc[e] += __shfl_xor(acc[e], 32, 64);
            }
            float p[6];
#pragma unroll
            for (int e = 0; e < 6; ++e) p[e] = acc[e] + pb[e];
            const float fx = (n2 < 64) ? (float)(n2 >> 3) : 0.0f;
            const float fy = (n2 < 64) ? (float)(n2 & 7) : 0.0f;
            float val = bias1;
            val = fmaf(fx, wsp0, val);
            val = fmaf(fy, wsp1, val);
#pragma unroll
            for (int c = 0; c < 6; ++c) val = fmaf(p[c], wc[c], val);
            float* dst = is_u ? uL : vL;
            dst[n2 * P + k] = val;
            if (lane == 0) colL[n2] = acc[6] + cb;
        }
    }

    __syncthreads();

    // ---- Phase B prologue: hoist this lane's i-invariant v/col[j] into regs
    float vv[5][8];
    float cjv[5];
#pragma unroll
    for (int jt = 0; jt < 5; ++jt) {
        const int j = jt * 16 + e16;           // j==79 reads defined padding
        const float4 va = *(const float4*)(vL + j * P + k0);
        const float4 vb = *(const float4*)(vL + j * P + k0 + 4);
        vv[jt][0] = va.x; vv[jt][1] = va.y; vv[jt][2] = va.z; vv[jt][3] = va.w;
        vv[jt][4] = vb.x; vv[jt][5] = vb.y; vv[jt][6] = vb.z; vv[jt][7] = vb.w;
        cjv[jt] = colL[j];
    }

    // ------- Phase B: this block's half of the i-range -------
    const int ilo = half ? 40 : 0;
    const int ihi = half ? SEQ : 40;
    const size_t obb = (size_t)b * (8 * NPB);
    for (int i = ilo + wv; i < ihi; i += NWAVES) {
        const float4 ua = *(const float4*)(uL + i * P + k0);   // per-i LDS
        const float4 ub = *(const float4*)(uL + i * P + k0 + 4);
        const float ci = colL[i];
        const float uu[8] = {ua.x, ua.y, ua.z, ua.w, ub.x, ub.y, ub.z, ub.w};

#pragma unroll
        for (int jt = 0; jt < 5; ++jt) {
            const int j = jt * 16 + e16;
            const float sw = (ci == cjv[jt]) ? 1.0f : 0.0f;
            const v2f swp = {sw, sw};

            union { unsigned w[4]; short8 s; } B;
#pragma unroll
            for (int w = 0; w < 4; ++w) {
                v2f a = {uu[2 * w] + vv[jt][2 * w], uu[2 * w + 1] + vv[jt][2 * w + 1]};
                a = a + swp * w14p[w];
                const v2f h = gelu2(a);
                B.w[w] = cvt_pk_bf16(h.x, h.y);
            }

            f32x4 acc2 = {0.f, 0.f, 0.f, 0.f};
            acc2 = __builtin_amdgcn_mfma_f32_16x16x32_bf16(A.s, B.s, acc2, 0, 0, 0);

            // D: col = e16 (j), row = kq*4+q (e); rows 0..7 valid
            if (kq < 2 && j < SEQ) {
                float* o = out + obb + (size_t)(kq * 4) * NPB + (size_t)i * SEQ + j;
#pragma unroll
                for (int q = 0; q < 4; ++q)
                    o[(size_t)q * NPB] = acc2[q] + b2v[q];
            }
        }
    }
}

extern "C" void kernel_launch(void* const* d_in, const int* in_sizes, int n_in,
                              void* d_out, int out_size, void* d_ws, size_t ws_size,
                              hipStream_t stream) {
    const float* x       = (const float*)d_in[0];
    const float* piece_w = (const float*)d_in[1];
    const float* piece_b = (const float*)d_in[2];
    const float* color_w = (const float*)d_in[3];
    const float* color_b = (const float*)d_in[4];
    const float* mlp1_w  = (const float*)d_in[5];
    const float* mlp1_b  = (const float*)d_in[6];
    const float* mlp2_w  = (const float*)d_in[7];
    const float* mlp2_b  = (const float*)d_in[8];
    float* out = (float*)d_out;

    hipLaunchKernelGGL(fused_bias, dim3(BATCHN * 2), dim3(256), 0, stream,
                       x, piece_w, piece_b, color_w, color_b,
                       mlp1_w, mlp1_b, mlp2_w, mlp2_b, out);
}

// Round 25
// 67.011 us; speedup vs baseline: 1.3403x; 1.3403x over previous
//
#include <hip/hip_runtime.h>

#define SEQ 79
#define DM 1024
#define BATCHN 512
#define NPB (SEQ * SEQ)             // 6241
#define P 36                        // k-pitch in floats (16B-aligned, odd/32 banks)
#define NWAVES 4                    // 256-thread block

typedef float v2f   __attribute__((ext_vector_type(2)));
typedef float f32x4 __attribute__((ext_vector_type(4)));
typedef short short8 __attribute__((ext_vector_type(8)));

__device__ __forceinline__ unsigned cvt_pk_bf16(float lo, float hi) {
    unsigned r;
    asm("v_cvt_pk_bf16_f32 %0, %1, %2" : "=v"(r) : "v"(lo), "v"(hi));
    return r;
}

// DPP lane-shuffle add on the VALU pipe: 0xB1=xor1, 0x4E=xor2, 0x124=row_ror:4,
// 0x128=row_ror:8 -> 16-lane sums after 4 steps. (R16-proven.)
template <int CTRL>
__device__ __forceinline__ float dpp_add(float v) {
    int t = __builtin_amdgcn_update_dpp(0, __builtin_bit_cast(int, v),
                                        CTRL, 0xf, 0xf, false);
    return v + __builtin_bit_cast(float, t);
}

__device__ __forceinline__ v2f gelu2(v2f a) {
    // gelu(a) = a - a / (exp2(c1*a + c2*a^3) + 1)
    const v2f C1 = {2.3022585093f, 2.3022585093f};
    const v2f C2 = {0.1029450750f, 0.1029450750f};
    v2f tt = a * (a * a * C2 + C1);
    v2f e;
    e.x = __builtin_amdgcn_exp2f(tt.x);
    e.y = __builtin_amdgcn_exp2f(tt.y);
    v2f ep = e + (v2f){1.f, 1.f};
    v2f r;
    r.x = __builtin_amdgcn_rcpf(ep.x);
    r.y = __builtin_amdgcn_rcpf(ep.y);
    return a - a * r;
}

// R19 body (passing, 68.9us) with ONE change: MFMA operands SWAPPED so the
// output is j-major instead of e-major.
//   old: D = W2^T x H -> lane holds 4 values strided by NPB -> 8 scalar
//        stores per subtile (40/i-iter), half-lane-masked.
//   new: D = H x W2   -> lane (e=lane&15, e<8 valid) holds 4 j-CONSECUTIVE
//        values -> ONE 16B memcpy store per lane per subtile (R4-proven
//        legal on 4B-aligned addresses), fully 64B-segment-coalesced.
// Fragment layouts of A and B operands are symmetric (outer=lane&15,
// k=(lane>>4)*8+elem), so H computation and W2 packing bytes are UNCHANGED —
// only the intrinsic argument order flips. Tail subtile (rows 76..79):
// 3-scalar fallback; j==79 garbage never stored.
// Occupancy levers are closed (R9-R12,R23,R24 all measured-blocked);
// this targets the store-issue/queue pressure that remains in phase B.
__global__ __launch_bounds__(256) void fused_bias(
    const float* __restrict__ x,
    const float* __restrict__ piece_w, const float* __restrict__ piece_b,
    const float* __restrict__ color_w, const float* __restrict__ color_b,
    const float* __restrict__ mlp1_w,  const float* __restrict__ mlp1_b,
    const float* __restrict__ mlp2_w,  const float* __restrict__ mlp2_b,
    float* __restrict__ out)
{
    __shared__ float uL[80 * P];     // 11,520 B
    __shared__ float vL[80 * P];     // 11,520 B
    __shared__ float colL[80];

    const int tid  = threadIdx.x;
    const int lane = tid & 63;
    const int wv   = tid >> 6;       // wave id 0..3
    const int b    = blockIdx.x;
    const int k    = lane & 31;
    const bool is_u = (lane < 32);

    // ---- phase-A per-lane projection weights: c = q*256 + lane*4 + t
    float wp[4][4][7];
#pragma unroll
    for (int q = 0; q < 4; ++q)
#pragma unroll
        for (int t = 0; t < 4; ++t) {
            const int c = q * 256 + lane * 4 + t;
#pragma unroll
            for (int e = 0; e < 6; ++e) wp[q][t][e] = piece_w[c * 6 + e];
            wp[q][t][6] = color_w[c];
        }

    float wsp0 = mlp1_w[0 * 32 + k];
    float wsp1 = mlp1_w[1 * 32 + k];
    if (!is_u) { wsp0 = -wsp0; wsp1 = -wsp1; }
    const float bias1 = is_u ? mlp1_b[k] : 0.0f;
    float wc[6];
#pragma unroll
    for (int c = 0; c < 6; ++c)
        wc[c] = mlp1_w[((is_u ? 2 : 8) + c) * 32 + k];
    float pb[6];
#pragma unroll
    for (int e = 0; e < 6; ++e) pb[e] = piece_b[e];
    const float cb = color_b[0];

    // ---- phase-B lane constants
    const int e16 = lane & 15;          // W2 output index e (valid e<8)
    const int kq  = lane >> 4;          // k-quarter / j-row group
    const int k0  = kq * 8;

    union { unsigned w[4]; short8 s; } Wf;  // W2 fragment (now B-operand);
#pragma unroll                               // packing identical to old A
    for (int w = 0; w < 4; ++w) {
        const float lo = (e16 < 8) ? mlp2_w[(k0 + 2 * w) * 8 + e16] : 0.0f;
        const float hi = (e16 < 8) ? mlp2_w[(k0 + 2 * w + 1) * 8 + e16] : 0.0f;
        Wf.w[w] = cvt_pk_bf16(lo, hi);
    }
    v2f w14p[4];
#pragma unroll
    for (int w = 0; w < 4; ++w)
        w14p[w] = (v2f){mlp1_w[14 * 32 + k0 + 2 * w], mlp1_w[14 * 32 + k0 + 2 * w + 1]};
    const float b2 = (e16 < 8) ? mlp2_b[e16] : 0.0f;   // per-lane scalar bias

    // defined padding for row 79 (j==79 H garbage only reaches D row 15 of
    // the last subtile, whose store is tail-guarded)
    if (wv == 0) {
        if (lane < P) vL[79 * P + lane] = 0.0f;
        if (lane == 0) colL[79] = 0.0f;
    }

    // ---------------- Phase A: 79 token rows -> LDS, 2 rows/iteration -------
    const float* xb = x + (size_t)b * SEQ * DM;
    for (int n = wv; n < SEQ; n += 2 * NWAVES) {
        const int n2  = n + NWAVES;
        const int n2c = (n2 < SEQ) ? n2 : n;   // clamped: loads always defined

        // issue all 8 loads up front (row n2's fly under row n's compute)
        const float4* xr0 = (const float4*)(xb + (size_t)n * DM);
        const float4* xr1 = (const float4*)(xb + (size_t)n2c * DM);
        float4 xv0[4], xv1[4];
#pragma unroll
        for (int q = 0; q < 4; ++q) xv0[q] = xr0[q * 64 + lane];
#pragma unroll
        for (int q = 0; q < 4; ++q) xv1[q] = xr1[q * 64 + lane];

        // ---- row n
        {
            float acc[7] = {0.f, 0.f, 0.f, 0.f, 0.f, 0.f, 0.f};
#pragma unroll
            for (int q = 0; q < 4; ++q) {
                const float xs[4] = {xv0[q].x, xv0[q].y, xv0[q].z, xv0[q].w};
#pragma unroll
                for (int t = 0; t < 4; ++t)
#pragma unroll
                    for (int e = 0; e < 7; ++e)
                        acc[e] = fmaf(xs[t], wp[q][t][e], acc[e]);
            }
#pragma unroll
            for (int e = 0; e < 7; ++e) {
                acc[e] = dpp_add<0xB1>(acc[e]);
                acc[e] = dpp_add<0x4E>(acc[e]);
                acc[e] = dpp_add<0x124>(acc[e]);
                acc[e] = dpp_add<0x128>(acc[e]);
                acc[e] += __shfl_xor(acc[e], 16, 64);
                acc[e] += __shfl_xor(acc[e], 32, 64);
            }
            float p[6];
#pragma unroll
            for (int e = 0; e < 6; ++e) p[e] = acc[e] + pb[e];
            const float fx = (n < 64) ? (float)(n >> 3) : 0.0f;
            const float fy = (n < 64) ? (float)(n & 7) : 0.0f;
            float val = bias1;
            val = fmaf(fx, wsp0, val);
            val = fmaf(fy, wsp1, val);
#pragma unroll
            for (int c = 0; c < 6; ++c) val = fmaf(p[c], wc[c], val);
            float* dst = is_u ? uL : vL;
            dst[n * P + k] = val;
            if (lane == 0) colL[n] = acc[6] + cb;
        }

        // ---- row n2 (skipped entirely on the tail; loads were clamped)
        if (n2 < SEQ) {
            float acc[7] = {0.f, 0.f, 0.f, 0.f, 0.f, 0.f, 0.f};
#pragma unroll
            for (int q = 0; q < 4; ++q) {
                const float xs[4] = {xv1[q].x, xv1[q].y, xv1[q].z, xv1[q].w};
#pragma unroll
                for (int t = 0; t < 4; ++t)
#pragma unroll
                    for (int e = 0; e < 7; ++e)
                        acc[e] = fmaf(xs[t], wp[q][t][e], acc[e]);
            }
#pragma unroll
            for (int e = 0; e < 7; ++e) {
                acc[e] = dpp_add<0xB1>(acc[e]);
                acc[e] = dpp_add<0x4E>(acc[e]);
                acc[e] = dpp_add<0x124>(acc[e]);
                acc[e] = dpp_add<0x128>(acc[e]);
                acc[e] += __shfl_xor(acc[e], 16, 64);
                acc[e] += __shfl_xor(acc[e], 32, 64);
            }
            float p[6];
#pragma unroll
            for (int e = 0; e < 6; ++e) p[e] = acc[e] + pb[e];
            const float fx = (n2 < 64) ? (float)(n2 >> 3) : 0.0f;
            const float fy = (n2 < 64) ? (float)(n2 & 7) : 0.0f;
            float val = bias1;
            val = fmaf(fx, wsp0, val);
            val = fmaf(fy, wsp1, val);
#pragma unroll
            for (int c = 0; c < 6; ++c) val = fmaf(p[c], wc[c], val);
            float* dst = is_u ? uL : vL;
            dst[n2 * P + k] = val;
            if (lane == 0) colL[n2] = acc[6] + cb;
        }
    }

    __syncthreads();

    // ---- Phase B prologue: hoist this lane's i-invariant v/col[j] into regs
    // (lane's H-row index within each subtile is e16 -> j = jt*16 + e16,
    //  unchanged from R19)
    float vv[5][8];
    float cjv[5];
#pragma unroll
    for (int jt = 0; jt < 5; ++jt) {
        const int j = jt * 16 + e16;           // j==79 reads defined padding
        const float4 va = *(const float4*)(vL + j * P + k0);
        const float4 vb = *(const float4*)(vL + j * P + k0 + 4);
        vv[jt][0] = va.x; vv[jt][1] = va.y; vv[jt][2] = va.z; vv[jt][3] = va.w;
        vv[jt][4] = vb.x; vv[jt][5] = vb.y; vv[jt][6] = vb.z; vv[jt][7] = vb.w;
        cjv[jt] = colL[j];
    }

    // ------- Phase B: i-outer; inner 5 subtiles fully register-resident -----
    const size_t obb = (size_t)b * (8 * NPB);
    const int jr = 4 * kq;                    // this lane's D j-row offset
    for (int i = wv; i < SEQ; i += NWAVES) {
        const float4 ua = *(const float4*)(uL + i * P + k0);   // per-i LDS
        const float4 ub = *(const float4*)(uL + i * P + k0 + 4);
        const float ci = colL[i];
        const float uu[8] = {ua.x, ua.y, ua.z, ua.w, ub.x, ub.y, ub.z, ub.w};

#pragma unroll
        for (int jt = 0; jt < 5; ++jt) {
            const float sw = (ci == cjv[jt]) ? 1.0f : 0.0f;
            const v2f swp = {sw, sw};

            union { unsigned w[4]; short8 s; } Hf;
#pragma unroll
            for (int w = 0; w < 4; ++w) {
                v2f a = {uu[2 * w] + vv[jt][2 * w], uu[2 * w + 1] + vv[jt][2 * w + 1]};
                a = a + swp * w14p[w];
                const v2f h = gelu2(a);
                Hf.w[w] = cvt_pk_bf16(h.x, h.y);
            }

            f32x4 acc2 = {0.f, 0.f, 0.f, 0.f};
            // D = H x W2: rows = j (A-rows), cols = e (B-cols)
            acc2 = __builtin_amdgcn_mfma_f32_16x16x32_bf16(Hf.s, Wf.s, acc2, 0, 0, 0);

            // D: col = e16 = e, row = jr+q = j-in-subtile -> lane's 4 accs
            // are j-CONSECUTIVE: one 16B store (4B-aligned -> memcpy).
            if (e16 < 8) {
                const int j0 = jt * 16 + jr;
                float* o = out + obb + (size_t)e16 * NPB + (size_t)i * SEQ + j0;
                float res[4] = {acc2[0] + b2, acc2[1] + b2,
                                acc2[2] + b2, acc2[3] + b2};
                if (j0 + 3 < SEQ) {
                    __builtin_memcpy(o, res, 16);
                } else {                     // j0 == 76: rows 76..78 only
                    o[0] = res[0]; o[1] = res[1]; o[2] = res[2];
                }
            }
        }
    }
}

extern "C" void kernel_launch(void* const* d_in, const int* in_sizes, int n_in,
                              void* d_out, int out_size, void* d_ws, size_t ws_size,
                              hipStream_t stream) {
    const float* x       = (const float*)d_in[0];
    const float* piece_w = (const float*)d_in[1];
    const float* piece_b = (const float*)d_in[2];
    const float* color_w = (const float*)d_in[3];
    const float* color_b = (const float*)d_in[4];
    const float* mlp1_w  = (const float*)d_in[5];
    const float* mlp1_b  = (const float*)d_in[6];
    const float* mlp2_w  = (const float*)d_in[7];
    const float* mlp2_b  = (const float*)d_in[8];
    float* out = (float*)d_out;

    hipLaunchKernelGGL(fused_bias, dim3(BATCHN), dim3(256), 0, stream,
                       x, piece_w, piece_b, color_w, color_b,
                       mlp1_w, mlp1_b, mlp2_w, mlp2_b, out);
}

// Round 26
// 66.548 us; speedup vs baseline: 1.3496x; 1.0069x over previous
//
#include <hip/hip_runtime.h>

#define SEQ 79
#define DM 1024
#define BATCHN 512
#define NPB (SEQ * SEQ)             // 6241
#define P 36                        // k-pitch in floats (16B-aligned, odd/32 banks)
#define NWAVES 4                    // 256-thread block

typedef float v2f   __attribute__((ext_vector_type(2)));
typedef float f32x4 __attribute__((ext_vector_type(4)));
typedef short short8 __attribute__((ext_vector_type(8)));

__device__ __forceinline__ unsigned cvt_pk_bf16(float lo, float hi) {
    unsigned r;
    asm("v_cvt_pk_bf16_f32 %0, %1, %2" : "=v"(r) : "v"(lo), "v"(hi));
    return r;
}

// DPP lane-shuffle add on the VALU pipe: 0xB1=xor1, 0x4E=xor2, 0x124=row_ror:4,
// 0x128=row_ror:8 -> 16-lane sums after 4 steps. (R16-proven.)
template <int CTRL>
__device__ __forceinline__ float dpp_add(float v) {
    int t = __builtin_amdgcn_update_dpp(0, __builtin_bit_cast(int, v),
                                        CTRL, 0xf, 0xf, false);
    return v + __builtin_bit_cast(float, t);
}

__device__ __forceinline__ v2f gelu2(v2f a) {
    // gelu(a) = a - a / (exp2(c1*a + c2*a^3) + 1)
    const v2f C1 = {2.3022585093f, 2.3022585093f};
    const v2f C2 = {0.1029450750f, 0.1029450750f};
    v2f tt = a * (a * a * C2 + C1);
    v2f e;
    e.x = __builtin_amdgcn_exp2f(tt.x);
    e.y = __builtin_amdgcn_exp2f(tt.y);
    v2f ep = e + (v2f){1.f, 1.f};
    v2f r;
    r.x = __builtin_amdgcn_rcpf(ep.x);
    r.y = __builtin_amdgcn_rcpf(ep.y);
    return a - a * r;
}

// R25 base (passing, 67.0us: j-major MFMA output, 16B coalesced stores) with
// ONE change: phase B processes TWO i-rows per iteration (i0 = wv+8m, i1 =
// i0+4) as straight-line dual bodies — all 6 LDS loads (u x2 halves x2 rows
// + col x2) issued up front, body-0's ~640cy of gelu/MFMA hides body-1's
// LDS latency. R15-proven shape: no loop-carried registers, clamped i1 load
// index (uL row 79 never written -> clamp to 78), body-1 guarded by the
// WAVE-UNIFORM i1 < SEQ (cheap branch).
// Occupancy levers remain closed (R9-R12, R23, R24 measured-blocked).
__global__ __launch_bounds__(256) void fused_bias(
    const float* __restrict__ x,
    const float* __restrict__ piece_w, const float* __restrict__ piece_b,
    const float* __restrict__ color_w, const float* __restrict__ color_b,
    const float* __restrict__ mlp1_w,  const float* __restrict__ mlp1_b,
    const float* __restrict__ mlp2_w,  const float* __restrict__ mlp2_b,
    float* __restrict__ out)
{
    __shared__ float uL[80 * P];     // 11,520 B
    __shared__ float vL[80 * P];     // 11,520 B
    __shared__ float colL[80];

    const int tid  = threadIdx.x;
    const int lane = tid & 63;
    const int wv   = tid >> 6;       // wave id 0..3
    const int b    = blockIdx.x;
    const int k    = lane & 31;
    const bool is_u = (lane < 32);

    // ---- phase-A per-lane projection weights: c = q*256 + lane*4 + t
    float wp[4][4][7];
#pragma unroll
    for (int q = 0; q < 4; ++q)
#pragma unroll
        for (int t = 0; t < 4; ++t) {
            const int c = q * 256 + lane * 4 + t;
#pragma unroll
            for (int e = 0; e < 6; ++e) wp[q][t][e] = piece_w[c * 6 + e];
            wp[q][t][6] = color_w[c];
        }

    float wsp0 = mlp1_w[0 * 32 + k];
    float wsp1 = mlp1_w[1 * 32 + k];
    if (!is_u) { wsp0 = -wsp0; wsp1 = -wsp1; }
    const float bias1 = is_u ? mlp1_b[k] : 0.0f;
    float wc[6];
#pragma unroll
    for (int c = 0; c < 6; ++c)
        wc[c] = mlp1_w[((is_u ? 2 : 8) + c) * 32 + k];
    float pb[6];
#pragma unroll
    for (int e = 0; e < 6; ++e) pb[e] = piece_b[e];
    const float cb = color_b[0];

    // ---- phase-B lane constants
    const int e16 = lane & 15;          // W2 output index e (valid e<8)
    const int kq  = lane >> 4;          // k-quarter / j-row group
    const int k0  = kq * 8;

    union { unsigned w[4]; short8 s; } Wf;  // W2 fragment (B-operand)
#pragma unroll
    for (int w = 0; w < 4; ++w) {
        const float lo = (e16 < 8) ? mlp2_w[(k0 + 2 * w) * 8 + e16] : 0.0f;
        const float hi = (e16 < 8) ? mlp2_w[(k0 + 2 * w + 1) * 8 + e16] : 0.0f;
        Wf.w[w] = cvt_pk_bf16(lo, hi);
    }
    v2f w14p[4];
#pragma unroll
    for (int w = 0; w < 4; ++w)
        w14p[w] = (v2f){mlp1_w[14 * 32 + k0 + 2 * w], mlp1_w[14 * 32 + k0 + 2 * w + 1]};
    const float b2 = (e16 < 8) ? mlp2_b[e16] : 0.0f;   // per-lane scalar bias

    // defined padding for row 79 (j==79 H garbage only reaches tail-guarded D)
    if (wv == 0) {
        if (lane < P) vL[79 * P + lane] = 0.0f;
        if (lane == 0) colL[79] = 0.0f;
    }

    // ---------------- Phase A: 79 token rows -> LDS, 2 rows/iteration -------
    const float* xb = x + (size_t)b * SEQ * DM;
    for (int n = wv; n < SEQ; n += 2 * NWAVES) {
        const int n2  = n + NWAVES;
        const int n2c = (n2 < SEQ) ? n2 : n;   // clamped: loads always defined

        // issue all 8 loads up front (row n2's fly under row n's compute)
        const float4* xr0 = (const float4*)(xb + (size_t)n * DM);
        const float4* xr1 = (const float4*)(xb + (size_t)n2c * DM);
        float4 xv0[4], xv1[4];
#pragma unroll
        for (int q = 0; q < 4; ++q) xv0[q] = xr0[q * 64 + lane];
#pragma unroll
        for (int q = 0; q < 4; ++q) xv1[q] = xr1[q * 64 + lane];

        // ---- row n
        {
            float acc[7] = {0.f, 0.f, 0.f, 0.f, 0.f, 0.f, 0.f};
#pragma unroll
            for (int q = 0; q < 4; ++q) {
                const float xs[4] = {xv0[q].x, xv0[q].y, xv0[q].z, xv0[q].w};
#pragma unroll
                for (int t = 0; t < 4; ++t)
#pragma unroll
                    for (int e = 0; e < 7; ++e)
                        acc[e] = fmaf(xs[t], wp[q][t][e], acc[e]);
            }
#pragma unroll
            for (int e = 0; e < 7; ++e) {
                acc[e] = dpp_add<0xB1>(acc[e]);
                acc[e] = dpp_add<0x4E>(acc[e]);
                acc[e] = dpp_add<0x124>(acc[e]);
                acc[e] = dpp_add<0x128>(acc[e]);
                acc[e] += __shfl_xor(acc[e], 16, 64);
                acc[e] += __shfl_xor(acc[e], 32, 64);
            }
            float p[6];
#pragma unroll
            for (int e = 0; e < 6; ++e) p[e] = acc[e] + pb[e];
            const float fx = (n < 64) ? (float)(n >> 3) : 0.0f;
            const float fy = (n < 64) ? (float)(n & 7) : 0.0f;
            float val = bias1;
            val = fmaf(fx, wsp0, val);
            val = fmaf(fy, wsp1, val);
#pragma unroll
            for (int c = 0; c < 6; ++c) val = fmaf(p[c], wc[c], val);
            float* dst = is_u ? uL : vL;
            dst[n * P + k] = val;
            if (lane == 0) colL[n] = acc[6] + cb;
        }

        // ---- row n2 (skipped entirely on the tail; loads were clamped)
        if (n2 < SEQ) {
            float acc[7] = {0.f, 0.f, 0.f, 0.f, 0.f, 0.f, 0.f};
#pragma unroll
            for (int q = 0; q < 4; ++q) {
                const float xs[4] = {xv1[q].x, xv1[q].y, xv1[q].z, xv1[q].w};
#pragma unroll
                for (int t = 0; t < 4; ++t)
#pragma unroll
                    for (int e = 0; e < 7; ++e)
                        acc[e] = fmaf(xs[t], wp[q][t][e], acc[e]);
            }
#pragma unroll
            for (int e = 0; e < 7; ++e) {
                acc[e] = dpp_add<0xB1>(acc[e]);
                acc[e] = dpp_add<0x4E>(acc[e]);
                acc[e] = dpp_add<0x124>(acc[e]);
                acc[e] = dpp_add<0x128>(acc[e]);
                acc[e] += __shfl_xor(acc[e], 16, 64);
                acc[e] += __shfl_xor(acc[e], 32, 64);
            }
            float p[6];
#pragma unroll
            for (int e = 0; e < 6; ++e) p[e] = acc[e] + pb[e];
            const float fx = (n2 < 64) ? (float)(n2 >> 3) : 0.0f;
            const float fy = (n2 < 64) ? (float)(n2 & 7) : 0.0f;
            float val = bias1;
            val = fmaf(fx, wsp0, val);
            val = fmaf(fy, wsp1, val);
#pragma unroll
            for (int c = 0; c < 6; ++c) val = fmaf(p[c], wc[c], val);
            float* dst = is_u ? uL : vL;
            dst[n2 * P + k] = val;
            if (lane == 0) colL[n2] = acc[6] + cb;
        }
    }

    __syncthreads();

    // ---- Phase B prologue: hoist this lane's i-invariant v/col[j] into regs
    float vv[5][8];
    float cjv[5];
#pragma unroll
    for (int jt = 0; jt < 5; ++jt) {
        const int j = jt * 16 + e16;           // j==79 reads defined padding
        const float4 va = *(const float4*)(vL + j * P + k0);
        const float4 vb = *(const float4*)(vL + j * P + k0 + 4);
        vv[jt][0] = va.x; vv[jt][1] = va.y; vv[jt][2] = va.z; vv[jt][3] = va.w;
        vv[jt][4] = vb.x; vv[jt][5] = vb.y; vv[jt][6] = vb.z; vv[jt][7] = vb.w;
        cjv[jt] = colL[j];
    }

    // ------- Phase B: dual-i iterations; all LDS loads issued up front ------
    const size_t obb = (size_t)b * (8 * NPB);
    const int jr = 4 * kq;                    // this lane's D j-row offset
#pragma unroll 2
    for (int m = 0; m < 10; ++m) {
        const int i0 = wv + m * 8;            // wv + 0..72, always < 79
        const int i1 = i0 + 4;                // 79 possible (wv=3, m=9)
        const bool has1 = (i1 < SEQ);         // wave-uniform guard
        const int i1c = has1 ? i1 : (SEQ - 1);

        // all 6 LDS loads up front (body-0 compute hides body-1 latency)
        const float4 ua0 = *(const float4*)(uL + i0 * P + k0);
        const float4 ub0 = *(const float4*)(uL + i0 * P + k0 + 4);
        const float ci0 = colL[i0];
        const float4 ua1 = *(const float4*)(uL + i1c * P + k0);
        const float4 ub1 = *(const float4*)(uL + i1c * P + k0 + 4);
        const float ci1 = colL[i1c];

        // ---- body 0 (i0 always valid)
        {
            const float uu[8] = {ua0.x, ua0.y, ua0.z, ua0.w,
                                 ub0.x, ub0.y, ub0.z, ub0.w};
#pragma unroll
            for (int jt = 0; jt < 5; ++jt) {
                const float sw = (ci0 == cjv[jt]) ? 1.0f : 0.0f;
                const v2f swp = {sw, sw};
                union { unsigned w[4]; short8 s; } Hf;
#pragma unroll
                for (int w = 0; w < 4; ++w) {
                    v2f a = {uu[2 * w] + vv[jt][2 * w],
                             uu[2 * w + 1] + vv[jt][2 * w + 1]};
                    a = a + swp * w14p[w];
                    const v2f h = gelu2(a);
                    Hf.w[w] = cvt_pk_bf16(h.x, h.y);
                }
                f32x4 acc2 = {0.f, 0.f, 0.f, 0.f};
                acc2 = __builtin_amdgcn_mfma_f32_16x16x32_bf16(Hf.s, Wf.s, acc2, 0, 0, 0);
                if (e16 < 8) {
                    const int j0 = jt * 16 + jr;
                    float* o = out + obb + (size_t)e16 * NPB + (size_t)i0 * SEQ + j0;
                    float res[4] = {acc2[0] + b2, acc2[1] + b2,
                                    acc2[2] + b2, acc2[3] + b2};
                    if (j0 + 3 < SEQ) { __builtin_memcpy(o, res, 16); }
                    else { o[0] = res[0]; o[1] = res[1]; o[2] = res[2]; }
                }
            }
        }

        // ---- body 1 (wave-uniform guard; loads were clamped-defined)
        if (has1) {
            const float uu[8] = {ua1.x, ua1.y, ua1.z, ua1.w,
                                 ub1.x, ub1.y, ub1.z, ub1.w};
#pragma unroll
            for (int jt = 0; jt < 5; ++jt) {
                const float sw = (ci1 == cjv[jt]) ? 1.0f : 0.0f;
                const v2f swp = {sw, sw};
                union { unsigned w[4]; short8 s; } Hf;
#pragma unroll
                for (int w = 0; w < 4; ++w) {
                    v2f a = {uu[2 * w] + vv[jt][2 * w],
                             uu[2 * w + 1] + vv[jt][2 * w + 1]};
                    a = a + swp * w14p[w];
                    const v2f h = gelu2(a);
                    Hf.w[w] = cvt_pk_bf16(h.x, h.y);
                }
                f32x4 acc2 = {0.f, 0.f, 0.f, 0.f};
                acc2 = __builtin_amdgcn_mfma_f32_16x16x32_bf16(Hf.s, Wf.s, acc2, 0, 0, 0);
                if (e16 < 8) {
                    const int j0 = jt * 16 + jr;
                    float* o = out + obb + (size_t)e16 * NPB + (size_t)i1 * SEQ + j0;
                    float res[4] = {acc2[0] + b2, acc2[1] + b2,
                                    acc2[2] + b2, acc2[3] + b2};
                    if (j0 + 3 < SEQ) { __builtin_memcpy(o, res, 16); }
                    else { o[0] = res[0]; o[1] = res[1]; o[2] = res[2]; }
                }
            }
        }
    }
}

extern "C" void kernel_launch(void* const* d_in, const int* in_sizes, int n_in,
                              void* d_out, int out_size, void* d_ws, size_t ws_size,
                              hipStream_t stream) {
    const float* x       = (const float*)d_in[0];
    const float* piece_w = (const float*)d_in[1];
    const float* piece_b = (const float*)d_in[2];
    const float* color_w = (const float*)d_in[3];
    const float* color_b = (const float*)d_in[4];
    const float* mlp1_w  = (const float*)d_in[5];
    const float* mlp1_b  = (const float*)d_in[6];
    const float* mlp2_w  = (const float*)d_in[7];
    const float* mlp2_b  = (const float*)d_in[8];
    float* out = (float*)d_out;

    hipLaunchKernelGGL(fused_bias, dim3(BATCHN), dim3(256), 0, stream,
                       x, piece_w, piece_b, color_w, color_b,
                       mlp1_w, mlp1_b, mlp2_w, mlp2_b, out);
}